// Round 1
// baseline (173.950 us; speedup 1.0000x reference)
//
#include <hip/hip_runtime.h>

#define LN_EPS 1e-5f

// Sizes fixed by the problem: B=32, TF=2048, C=32, D=8, HID=EG=32.
// rows = B*TF*C = 2,097,152 independent rows of 8 inputs -> 32 outputs.

// d_ws float layout:
//   [0,256)     M1 = A@W1   (32 x 8)
//   [256,288)   c1 = A@b1   (32)
//   [288,1312)  M2 = A@W2   (32 x 32)
//   [1312,1344) c2 = A@b2   (32)

__global__ void gnn_prologue(const float* __restrict__ adjacency,
                             const float* __restrict__ W1,
                             const float* __restrict__ b1,
                             const float* __restrict__ W2,
                             const float* __restrict__ b2,
                             float* __restrict__ ws) {
    __shared__ float dis[32];
    __shared__ float na[32][32];
    const int t = threadIdx.x;
    if (t < 32) {
        float s = 1.0f;  // self-loop contributes 1 to the degree
        for (int j = 0; j < 32; ++j) s += adjacency[t * 32 + j];
        dis[t] = rsqrtf(s + 1e-6f);   // (deg + 1e-6)^-0.5
    }
    __syncthreads();
    for (int idx = t; idx < 1024; idx += blockDim.x) {
        const int i = idx >> 5, j = idx & 31;
        const float a = adjacency[idx] + (i == j ? 1.0f : 0.0f);
        na[i][j] = dis[i] * a * dis[j];
    }
    __syncthreads();
    // M2 = na @ W2   (W2 is [32,32] row-major: W2[j][k])
    for (int idx = t; idx < 1024; idx += blockDim.x) {
        const int i = idx >> 5, k = idx & 31;
        float a = 0.0f;
        for (int j = 0; j < 32; ++j) a += na[i][j] * W2[j * 32 + k];
        ws[288 + idx] = a;
    }
    // M1 = na @ W1   (W1 is [32,8] row-major: W1[j][d])
    for (int idx = t; idx < 256; idx += blockDim.x) {
        const int i = idx >> 3, d = idx & 7;
        float a = 0.0f;
        for (int j = 0; j < 32; ++j) a += na[i][j] * W1[j * 8 + d];
        ws[idx] = a;
    }
    // c1 = na @ b1, c2 = na @ b2
    if (t < 32) {
        float a1 = 0.0f, a2 = 0.0f;
        for (int j = 0; j < 32; ++j) {
            a1 += na[t][j] * b1[j];
            a2 += na[t][j] * b2[j];
        }
        ws[256 + t]  = a1;
        ws[1312 + t] = a2;
    }
}

__device__ __forceinline__ void ln32(float* __restrict__ h,
                                     const float* __restrict__ g,
                                     const float* __restrict__ b) {
    float s = 0.0f;
#pragma unroll
    for (int i = 0; i < 32; ++i) s += h[i];
    const float m = s * 0.03125f;
    float v = 0.0f;
#pragma unroll
    for (int i = 0; i < 32; ++i) { const float d = h[i] - m; v = fmaf(d, d, v); }
    const float r = rsqrtf(v * 0.03125f + LN_EPS);
#pragma unroll
    for (int i = 0; i < 32; ++i) h[i] = fmaf((h[i] - m) * r, g[i], b[i]);
}

__global__ __launch_bounds__(256, 2) void gnn_main(
        const float* __restrict__ x,
        const float* __restrict__ ws,
        const float* __restrict__ g1v, const float* __restrict__ be1v,
        const float* __restrict__ g2v, const float* __restrict__ be2v,
        float* __restrict__ out) {
    __shared__ float m1s[256];
    __shared__ float m2s[1024];
    __shared__ float c1s[32], c2s[32];
    __shared__ float g1s[32], be1s[32], g2s[32], be2s[32];
    const int t = threadIdx.x;
    m1s[t] = ws[t];
#pragma unroll
    for (int q = 0; q < 4; ++q) m2s[t + q * 256] = ws[288 + t + q * 256];
    if (t < 32) {
        c1s[t]  = ws[256 + t];
        c2s[t]  = ws[1312 + t];
        g1s[t]  = g1v[t];  be1s[t] = be1v[t];
        g2s[t]  = g2v[t];  be2s[t] = be2v[t];
    }
    __syncthreads();

    // 2 rows per thread: r0 = blk*512 + t, r1 = r0 + 256 (coalesced loads/stores)
    const long long r0 = (long long)blockIdx.x * 512 + t;
    const long long r1 = r0 + 256;

    const float4* xv = (const float4*)x;
    const float4 p00 = xv[r0 * 2], p01 = xv[r0 * 2 + 1];
    const float4 p10 = xv[r1 * 2], p11 = xv[r1 * 2 + 1];
    const float xr0[8] = {p00.x, p00.y, p00.z, p00.w, p01.x, p01.y, p01.z, p01.w};
    const float xr1[8] = {p10.x, p10.y, p10.z, p10.w, p11.x, p11.y, p11.z, p11.w};

    // stage 1: h = relu(M1 @ x + c1) then LN
    float h0[32], h1[32];
#pragma unroll
    for (int i = 0; i < 32; ++i) {
        float s0 = c1s[i], s1 = s0;
#pragma unroll
        for (int d = 0; d < 8; ++d) {
            const float w = m1s[i * 8 + d];
            s0 = fmaf(xr0[d], w, s0);
            s1 = fmaf(xr1[d], w, s1);
        }
        h0[i] = fmaxf(s0, 0.0f);
        h1[i] = fmaxf(s1, 0.0f);
    }
    ln32(h0, g1s, be1s);
    ln32(h1, g1s, be1s);

    // stage 2: y = relu(M2 @ h + c2) then LN
    float y0[32], y1[32];
#pragma unroll
    for (int i = 0; i < 32; ++i) {
        float s0 = c2s[i], s1 = s0;
#pragma unroll
        for (int k = 0; k < 32; ++k) {
            const float w = m2s[i * 32 + k];   // wave-uniform -> LDS broadcast
            s0 = fmaf(h0[k], w, s0);
            s1 = fmaf(h1[k], w, s1);
        }
        y0[i] = fmaxf(s0, 0.0f);
        y1[i] = fmaxf(s1, 0.0f);
    }
    ln32(y0, g2s, be2s);
    ln32(y1, g2s, be2s);

    float4* ov = (float4*)out;
#pragma unroll
    for (int q = 0; q < 8; ++q)
        ov[r0 * 8 + q] = make_float4(y0[q * 4], y0[q * 4 + 1], y0[q * 4 + 2], y0[q * 4 + 3]);
#pragma unroll
    for (int q = 0; q < 8; ++q)
        ov[r1 * 8 + q] = make_float4(y1[q * 4], y1[q * 4 + 1], y1[q * 4 + 2], y1[q * 4 + 3]);
}

extern "C" void kernel_launch(void* const* d_in, const int* in_sizes, int n_in,
                              void* d_out, int out_size, void* d_ws, size_t ws_size,
                              hipStream_t stream) {
    const float* x   = (const float*)d_in[0];
    const float* adj = (const float*)d_in[1];
    const float* W1  = (const float*)d_in[2];
    const float* b1  = (const float*)d_in[3];
    const float* W2  = (const float*)d_in[4];
    const float* b2  = (const float*)d_in[5];
    const float* g1  = (const float*)d_in[6];
    const float* be1 = (const float*)d_in[7];
    const float* g2  = (const float*)d_in[8];
    const float* be2 = (const float*)d_in[9];
    float* out = (float*)d_out;
    float* ws  = (float*)d_ws;

    gnn_prologue<<<1, 256, 0, stream>>>(adj, W1, b1, W2, b2, ws);

    const int rows = 32 * 2048 * 32;          // 2,097,152
    gnn_main<<<rows / 512, 256, 0, stream>>>(x, ws, g1, be1, g2, be2, out);
}